// Round 10
// baseline (5466.154 us; speedup 1.0000x reference)
//
#include <hip/hip_runtime.h>
#include <math.h>

// 2-layer LSTM (H=512), T=1024 teacher steps + 64 AR steps; only batch row 255
// reaches the output -> single-sequence LSTM. Weights register-resident across
// persistent WGs. Per-tick all-to-all h exchange via SELF-VALIDATING pairs:
// each published value is a u64 (gen<<32 | bitcast(h)).
// R10: 32 WGs x 1024 threads (was 64x512). Same total lanes/protocol, but:
//  - tick latency = max over 32 publish chains (straggler tail halved)
//  - 1024 pairs / 1024 threads -> ONE pair per polling thread (single-load spin)
//  - publish still one wave-wide burst: wave 0 lanes 0..31 store the WG's
//    256 B line (16 h1 + 16 h2 pairs) in a single instruction.
// R9 lesson: 4x replication/128-pollers-per-line regressed -> contention is
// not the bottleneck. R8 lesson: pipelined polling regresses (vmcnt(0) drain).
// R7 lesson: multi-wave publication regresses (slowest-wave gating).
// 8B atomicity forbids torn reads; slot-reuse safe: a WG overwrites slot g&1
// (tag g+2) only after observing all tags g+1, which only exist after every
// WG's slot-(g&1) reads completed (reads drain before the barrier preceding
// their tag-(g+1) publish). Intra-WG: wave-internal shuffle reduce-scatter ->
// 8 row-sums/wave to LDS -> wave 0 applies gates (fast v_exp/v_rcp) and
// publishes. 2 __syncthreads per tick.

#define G     32      // workgroups
#define NT    1024    // threads/wg (16 waves)
#define HD    512     // hidden
#define TT    1024    // teacher steps
#define PRED  64      // prediction length
#define LINEU 32      // u64 pairs per comm line (256 B: 16 h1 + 16 h2)
#define SLOTU (G*LINEU)    // u64 per parity slot
#define STR   264     // hvec chunk stride in words (256 data + 8 pad banks)
#define AS    __HIP_MEMORY_SCOPE_AGENT

typedef unsigned long long u64;

#define LOG2E  1.44269504088896340736f

// opaque register pin (keeps one-time loads from being rematerialized)
#define KEEP4(v) asm volatile("" : "+v"(v.x), "+v"(v.y), "+v"(v.z), "+v"(v.w))

__device__ __forceinline__ float sigf(float x){
  return __builtin_amdgcn_rcpf(1.0f + __builtin_amdgcn_exp2f(-LOG2E * x));
}
__device__ __forceinline__ float tanhf_fast(float x){
  float e = __builtin_amdgcn_exp2f(2.0f * LOG2E * x);
  return 1.0f - 2.0f * __builtin_amdgcn_rcpf(e + 1.0f);
}
__device__ __forceinline__ float dot4(float4 a, float4 b){
  return a.x*b.x + a.y*b.y + a.z*b.z + a.w*b.w;
}

__global__ __launch_bounds__(NT, 1) void lstm2_kernel(
    const float* __restrict__ input,
    const float* __restrict__ Wih1, const float* __restrict__ Whh1,
    const float* __restrict__ bih1, const float* __restrict__ bhh1,
    const float* __restrict__ Wih2, const float* __restrict__ Whh2,
    const float* __restrict__ bih2, const float* __restrict__ bhh2,
    const float* __restrict__ Wlin, const float* __restrict__ blin,
    float* __restrict__ out, float* __restrict__ ws)
{
  // hvec chunk c (c=0..3) = words [c*STR, c*STR+256):
  //   c0: h1 unit U with (U>>2)&1==0 at word 4*(U>>3)+(U&3)   c1: other h1
  //   c2/c3: same for h2. Lane sg's float4 at [sg] = units 8sg..8sg+3 etc.
  __shared__ __align__(16) float hvec[4*STR];
  __shared__ __align__(16) float xrow[TT];
  __shared__ float pre[128];   // [0..63]=L1 rows (q*16+u), [64..127]=L2 rows

  u64* commu = (u64*)ws;       // [2][G][LINEU]

  const int t  = threadIdx.x;
  const int wg = blockIdx.x;
  const int rg = t >> 6;       // wave id 0..15
  const int sg = t & 63;       // lane

  xrow[t] = input[255*TT + t];

  // ---- weight preload: wg owns units [wg*16, wg*16+16) of both layers.
  // Wave rg handles local rows r = rg*4+k (r in [0,64): gate q=r>>4, unit
  // u=r&15) of BOTH layers -> global row R = q*512 + wg*16 + u.
  // Lane sg covers cols [8sg, 8sg+8).
  float4 w1[4][2], w2[4][4];
  #pragma unroll
  for (int k=0;k<4;k++){
    const int r = rg*4 + k;
    const int R = (r>>4)*HD + wg*16 + (r&15);
    const float* pa = Whh1 + R*HD + sg*8;
    w1[k][0] = *(const float4*)(pa);
    w1[k][1] = *(const float4*)(pa+4);
    const float* pb = Wih2 + R*HD + sg*8;
    const float* pc = Whh2 + R*HD + sg*8;
    w2[k][0] = *(const float4*)(pb);
    w2[k][1] = *(const float4*)(pb+4);
    w2[k][2] = *(const float4*)(pc);
    w2[k][3] = *(const float4*)(pc+4);
  }
  #pragma unroll
  for (int k=0;k<4;k++){
    KEEP4(w1[k][0]); KEEP4(w1[k][1]);
    KEEP4(w2[k][0]); KEEP4(w2[k][1]); KEEP4(w2[k][2]); KEEP4(w2[k][3]);
  }

  // combine lanes (wave 0): t<16 -> L1 unit t; t in [16,32) -> L2 unit t-16
  float bias[4]={0,0,0,0}, wx[4]={0,0,0,0};
  float cst  = 0.f;     // persistent cell state
  float hcur = 0.f;     // last h this lane produced (re-published every tick)
  if (t < 16){
    #pragma unroll
    for (int q=0;q<4;q++){
      int R = q*HD + wg*16 + t;
      bias[q] = bih1[R] + bhh1[R];
      wx[q]   = Wih1[R];
    }
  } else if (t < 32){
    #pragma unroll
    for (int q=0;q<4;q++){
      int R = q*HD + wg*16 + (t-16);
      bias[q] = bih2[R] + bhh2[R];
    }
  }
  float4 wl0={0,0,0,0}, wl1={0,0,0,0};
  if (t < 64){
    wl0 = *(const float4*)(Wlin + t*8);
    wl1 = *(const float4*)(Wlin + t*8 + 4);
  }
  const float blin0 = blin[0];

  // ---- consume tick g: thread t polls ONE pair (i=t&31) of line w=t>>5 ----
  auto poll_stage = [&](unsigned g){
    const int w = t >> 5, i = t & 31;
    const u64* dq = commu + (g & 1u)*SLOTU + w*LINEU + i;
    u64 q0;
    do { q0 = __hip_atomic_load(dq, __ATOMIC_RELAXED, AS); }
    while ((unsigned)(q0 >> 32) != g);
    // pair i: i<16 -> h1 unit w*16+i ; i>=16 -> h2 unit w*16+(i-16)
    const int U  = w*16 + (i & 15);
    const int c  = ((i < 16) ? 0 : 2) + ((U >> 2) & 1);
    const int wd = c*STR + 4*(U >> 3) + (U & 3);
    hvec[wd] = __builtin_bit_cast(float, (unsigned)q0);
    __syncthreads();
  };

  // ---- dots + wave-internal reduce-scatter; 8 row-sums/wave -> pre ----
  auto dots_reduce = [&](){
    const float4 c0 = ((const float4*)(hvec + 0*STR))[sg];
    const float4 c1 = ((const float4*)(hvec + 1*STR))[sg];
    const float4 c2 = ((const float4*)(hvec + 2*STR))[sg];
    const float4 c3 = ((const float4*)(hvec + 3*STR))[sg];
    float v[8];
    #pragma unroll
    for (int k=0;k<4;k++){
      v[k]   = dot4(w1[k][0],c0) + dot4(w1[k][1],c1);
      v[4+k] = dot4(w2[k][0],c0) + dot4(w2[k][1],c1)
             + dot4(w2[k][2],c2) + dot4(w2[k][3],c3);
    }
    const int b0 = sg & 1, b1 = (sg>>1)&1, b2 = (sg>>2)&1;
    float k4[4];
    #pragma unroll
    for (int k=0;k<4;k++){
      float x = b0 ? v[k] : v[k+4];
      float y = __shfl_xor(x, 1, 64);
      k4[k] = (b0 ? v[k+4] : v[k]) + y;
    }
    float k2[2];
    #pragma unroll
    for (int k=0;k<2;k++){
      float x = b1 ? k4[k] : k4[k+2];
      float y = __shfl_xor(x, 2, 64);
      k2[k] = (b1 ? k4[k+2] : k4[k]) + y;
    }
    float k1;
    {
      float x = b2 ? k2[0] : k2[1];
      float y = __shfl_xor(x, 4, 64);
      k1 = (b2 ? k2[1] : k2[0]) + y;
    }
    k1 += __shfl_xor(k1, 8, 64);
    k1 += __shfl_xor(k1, 16, 64);
    k1 += __shfl_xor(k1, 32, 64);
    if (sg < 8){
      const int j = b0*4 + b1*2 + b2;   // value index this lane holds
      if (j < 4) pre[rg*4 + j]        = k1;   // L1 row rg*4+j
      else       pre[64 + rg*4 + j-4] = k1;   // L2 row rg*4+(j-4)
    }
  };

  // ---- tail (wave 0): gather gates, apply, publish 32 pairs for g+1 ----
  auto tail = [&](unsigned g, bool d1, bool d2, float xv){
    if (rg == 0){
      const float rsumA = pre[t];        // L1 row t
      const float rsumB = pre[64 + t];   // L2 row t
      const int u = t & 15;
      float pi, pf, pg, po;
      {
        float a0 = __shfl(rsumA, u,      64), b0_ = __shfl(rsumB, u,      64);
        float a1 = __shfl(rsumA, u + 16, 64), b1_ = __shfl(rsumB, u + 16, 64);
        float a2 = __shfl(rsumA, u + 32, 64), b2_ = __shfl(rsumB, u + 32, 64);
        float a3 = __shfl(rsumA, u + 48, 64), b3_ = __shfl(rsumB, u + 48, 64);
        const bool l1 = (t < 16);
        pi = l1 ? a0 : b0_;
        pf = l1 ? a1 : b1_;
        pg = l1 ? a2 : b2_;
        po = l1 ? a3 : b3_;
      }
      const bool act = (t < 16) ? d1 : ((t < 32) ? d2 : false);
      if (act){
        if (t < 16){
          pi += xv*wx[0] + bias[0];
          pf += xv*wx[1] + bias[1];
          pg += xv*wx[2] + bias[2];
          po += xv*wx[3] + bias[3];
        } else {
          pi += bias[0]; pf += bias[1]; pg += bias[2]; po += bias[3];
        }
        cst  = sigf(pf)*cst + sigf(pi)*tanhf_fast(pg);
        hcur = sigf(po)*tanhf_fast(cst);
      }
      if (t < 32){
        u64 pr = ((u64)(g + 1u) << 32) | (u64)__builtin_bit_cast(unsigned, hcur);
        u64* nb = commu + ((g+1u) & 1u)*SLOTU + wg*LINEU + t;
        __hip_atomic_store(nb, pr, __ATOMIC_RELAXED, AS);
      }
    }
  };

  // o = Wlin . h2 + blin from hvec chunks 2/3; result in ALL wave-0 lanes
  auto computeO = [&](int oi, float& xv){
    if (rg == 0){
      float s = dot4(wl0, ((const float4*)(hvec + 2*STR))[t])
              + dot4(wl1, ((const float4*)(hvec + 3*STR))[t]);
      #pragma unroll
      for (int m=1;m<64;m<<=1) s += __shfl_xor(s, m, 64);
      xv = s + blin0;
      if (wg == 0 && t == 0) out[oi] = xv;
    }
  };

  __syncthreads();   // xrow staged

  unsigned g = 0;

  // ---- teacher: tick g computes L1 step g || L2 step g-1 ----
  for (int tk=0; tk<TT; ++tk, ++g){
    poll_stage(g);                       // hvec = [h1_{g-1} | h2_{g-2}]
    dots_reduce();
    __syncthreads();
    tail(g, true, tk >= 1, xrow[tk]);    // publish [h1_g | h2_{g-1}] pairs
  }

  // ---- drain: L2 step 1023 ----
  poll_stage(g);                         // [h1_1023 | h2_1022]
  dots_reduce();
  __syncthreads();
  tail(g, false, true, 0.f);             // publish [h1_1023 | h2_1023]
  ++g;

  // ---- AR: steps s = 1024..1086, 2 ticks each ----
  for (int s=TT; s<TT+PRED-1; ++s){
    poll_stage(g);                       // [h1_{s-1} | h2_{s-1}]
    float xv = 0.f;
    computeO(s - TT, xv);                // emit out[s-TT] (o_{s-1})
    dots_reduce();
    __syncthreads();
    tail(g, true, false, xv);            // publish [h1_s | h2_{s-1}]
    ++g;

    poll_stage(g);                       // [h1_s | h2_{s-1}]
    dots_reduce();
    __syncthreads();
    tail(g, false, true, 0.f);           // publish [h1_s | h2_s]
    ++g;
  }

  // ---- final output o_1086 ----
  poll_stage(g);                         // [h1_1086 | h2_1086]
  float xv;
  computeO(PRED - 1, xv);
}

extern "C" void kernel_launch(void* const* d_in, const int* in_sizes, int n_in,
                              void* d_out, int out_size, void* d_ws, size_t ws_size,
                              hipStream_t stream) {
  const float* input = (const float*)d_in[0];
  // d_in[1] = pred_len (fixed 64, baked in)
  const float* Wih1 = (const float*)d_in[2];
  const float* Whh1 = (const float*)d_in[3];
  const float* bih1 = (const float*)d_in[4];
  const float* bhh1 = (const float*)d_in[5];
  const float* Wih2 = (const float*)d_in[6];
  const float* Whh2 = (const float*)d_in[7];
  const float* bih2 = (const float*)d_in[8];
  const float* bhh2 = (const float*)d_in[9];
  const float* Wlin = (const float*)d_in[10];
  const float* blin = (const float*)d_in[11];

  // zero comm: u64 zero pairs == (gen 0, h=0.0f) -> valid initial state
  // 2 slots x 32 lines x 256 B = 16 KiB
  hipMemsetAsync(d_ws, 0, (size_t)2 * SLOTU * sizeof(u64), stream);

  lstm2_kernel<<<dim3(G), dim3(NT), 0, stream>>>(
      input, Wih1, Whh1, bih1, bhh1, Wih2, Whh2, bih2, bhh2, Wlin, blin,
      (float*)d_out, (float*)d_ws);
}

// Round 11
// 2711.797 us; speedup vs baseline: 2.0157x; 2.0157x over previous
//
#include <hip/hip_runtime.h>
#include <math.h>

// 2-layer LSTM (H=512), T=1024 teacher steps + 64 AR steps; only batch row 255
// reaches the output -> single-sequence LSTM. Weights register-resident across
// persistent WGs. Per-tick all-to-all h exchange via SELF-VALIDATING pairs:
// each published value is a u64 (gen<<32 | bitcast(h)).
// R11: 32 WGs x 512 threads. Halves the publish fan-in (tick latency = max
// over 32 jittered publish->detect chains, was 64) WITHOUT R10's fatal VGPR
// cap (1024-thr blocks forced 64 VGPR -> all weights spilled to scratch).
// Each WG owns 16 units/layer: 192 weight floats/thread (48 float4), ~240
// VGPRs at 512thr/__launch_bounds__(512,1) -> 2 waves/SIMD, 256 budget, fits.
// R9: replication/contention-splitting regressed -> contention not bottleneck.
// R8: pipelined polling regressed (vmcnt(0) drain). R7: multi-wave publish
// regressed (slowest-wave gating) -> wave-0 single-burst publish kept.
// 8B atomicity forbids torn reads; slot-reuse safe by barrier-ordered
// value-dependency causality (3-tick separation between overwrite and last
// read of a slot). Intra-WG: 16-value wave-internal shuffle reduce-scatter
// (17 shuffles, 6-stage depth) -> 16 row-sums/wave to LDS -> wave 0 applies
// gates (fast v_exp/v_rcp) and publishes. 2 __syncthreads per tick.

#define G     32      // workgroups
#define NT    512     // threads/wg (8 waves)
#define HD    512     // hidden
#define TT    1024    // teacher steps
#define PRED  64      // prediction length
#define LINEU 32      // u64 pairs per comm line (256 B: 16 h1 + 16 h2)
#define SLOTU (G*LINEU)    // u64 per parity slot
#define STR   264     // hvec chunk stride in words (256 data + 8 pad banks)
#define AS    __HIP_MEMORY_SCOPE_AGENT

typedef unsigned long long u64;

#define LOG2E  1.44269504088896340736f

// opaque register pin (keeps one-time loads from being rematerialized)
#define KEEP4(v) asm volatile("" : "+v"(v.x), "+v"(v.y), "+v"(v.z), "+v"(v.w))

__device__ __forceinline__ float sigf(float x){
  return __builtin_amdgcn_rcpf(1.0f + __builtin_amdgcn_exp2f(-LOG2E * x));
}
__device__ __forceinline__ float tanhf_fast(float x){
  float e = __builtin_amdgcn_exp2f(2.0f * LOG2E * x);
  return 1.0f - 2.0f * __builtin_amdgcn_rcpf(e + 1.0f);
}
__device__ __forceinline__ float dot4(float4 a, float4 b){
  return a.x*b.x + a.y*b.y + a.z*b.z + a.w*b.w;
}

__global__ __launch_bounds__(NT, 1) void lstm2_kernel(
    const float* __restrict__ input,
    const float* __restrict__ Wih1, const float* __restrict__ Whh1,
    const float* __restrict__ bih1, const float* __restrict__ bhh1,
    const float* __restrict__ Wih2, const float* __restrict__ Whh2,
    const float* __restrict__ bih2, const float* __restrict__ bhh2,
    const float* __restrict__ Wlin, const float* __restrict__ blin,
    float* __restrict__ out, float* __restrict__ ws)
{
  // hvec chunk c (c=0..3) = words [c*STR, c*STR+256):
  //   c0: h1 units U, (U>>2)&1==0, at word 4*(U>>3)+(U&3)   c1: other h1
  //   c2/c3: same for h2. Lane sg float4 at [sg]: c0 -> units 8sg..8sg+3 etc.
  __shared__ __align__(16) float hvec[4*STR];
  __shared__ __align__(16) float xrow[TT];
  __shared__ float pre[128];   // [0..63]=L1 rows (q*16+u), [64..127]=L2 rows

  u64* commu = (u64*)ws;       // [2][G][LINEU]

  const int t  = threadIdx.x;
  const int wg = blockIdx.x;
  const int rg = t >> 6;       // wave id 0..7
  const int sg = t & 63;       // lane

  ((float2*)xrow)[t] = ((const float2*)(input + 255*TT))[t];

  // ---- weight preload: wg owns units [wg*16, wg*16+16) of both layers.
  // Wave rg owns local rows r = rg*8+k (k=0..7) of the 64-row space
  // (row = q*16+u; gate q=r>>4, unit u=r&15) for BOTH layers:
  // global row R = q*512 + wg*16 + u. Lane sg covers cols [8sg, 8sg+8).
  float4 w1[8][2], w2[8][4];
  #pragma unroll
  for (int k=0;k<8;k++){
    const int r = rg*8 + k;
    const int R = (r>>4)*HD + wg*16 + (r&15);
    const float* pa = Whh1 + R*HD + sg*8;
    w1[k][0] = *(const float4*)(pa);
    w1[k][1] = *(const float4*)(pa+4);
    const float* pb = Wih2 + R*HD + sg*8;
    const float* pc = Whh2 + R*HD + sg*8;
    w2[k][0] = *(const float4*)(pb);
    w2[k][1] = *(const float4*)(pb+4);
    w2[k][2] = *(const float4*)(pc);
    w2[k][3] = *(const float4*)(pc+4);
  }
  #pragma unroll
  for (int k=0;k<8;k++){
    KEEP4(w1[k][0]); KEEP4(w1[k][1]);
    KEEP4(w2[k][0]); KEEP4(w2[k][1]); KEEP4(w2[k][2]); KEEP4(w2[k][3]);
  }

  // combine lanes (wave 0): t<16 -> L1 unit t; t in [16,32) -> L2 unit t-16
  float bias[4]={0,0,0,0}, wx[4]={0,0,0,0};
  float cst  = 0.f;     // persistent cell state
  float hcur = 0.f;     // last h this lane produced (re-published every tick)
  if (t < 16){
    #pragma unroll
    for (int q=0;q<4;q++){
      int R = q*HD + wg*16 + t;
      bias[q] = bih1[R] + bhh1[R];
      wx[q]   = Wih1[R];
    }
  } else if (t < 32){
    #pragma unroll
    for (int q=0;q<4;q++){
      int R = q*HD + wg*16 + (t-16);
      bias[q] = bih2[R] + bhh2[R];
    }
  }
  float4 wl0={0,0,0,0}, wl1={0,0,0,0};
  if (t < 64){
    wl0 = *(const float4*)(Wlin + t*8);
    wl1 = *(const float4*)(Wlin + t*8 + 4);
  }
  const float blin0 = blin[0];

  // ---- consume tick g: thread t polls pairs {2j,2j+1} of line w=t>>4 ----
  auto poll_stage = [&](unsigned g){
    const int w = t >> 4, j = t & 15;
    const u64* dq = commu + (g & 1u)*SLOTU + w*LINEU + 2*j;
    u64 q0, q1;
    do {
      q0 = __hip_atomic_load(dq,     __ATOMIC_RELAXED, AS);
      q1 = __hip_atomic_load(dq + 1, __ATOMIC_RELAXED, AS);
    } while ((unsigned)(q0 >> 32) != g || (unsigned)(q1 >> 32) != g);
    // pair i=2j: i<16 -> h1 units U,U+1 (U=w*16+i); i>=16 -> h2 units
    const int i0 = 2*j;
    const int U  = w*16 + (i0 & 15);
    const int c  = ((i0 < 16) ? 0 : 2) + ((U >> 2) & 1);
    const int wd = c*STR + 4*(U >> 3) + (U & 3);     // even -> 8B aligned
    float2 fv;
    fv.x = __builtin_bit_cast(float, (unsigned)q0);
    fv.y = __builtin_bit_cast(float, (unsigned)q1);
    *(float2*)(hvec + wd) = fv;
    __syncthreads();
  };

  // ---- dots + 16-value wave-internal reduce-scatter -> pre ----
  auto dots_reduce = [&](){
    const float4 c0 = ((const float4*)(hvec + 0*STR))[sg];
    const float4 c1 = ((const float4*)(hvec + 1*STR))[sg];
    const float4 c2 = ((const float4*)(hvec + 2*STR))[sg];
    const float4 c3 = ((const float4*)(hvec + 3*STR))[sg];
    float v[16];
    #pragma unroll
    for (int k=0;k<8;k++){
      v[k]   = dot4(w1[k][0],c0) + dot4(w1[k][1],c1);
      v[8+k] = dot4(w2[k][0],c0) + dot4(w2[k][1],c1)
             + dot4(w2[k][2],c2) + dot4(w2[k][3],c3);
    }
    const int b0 = sg & 1, b1 = (sg>>1)&1, b2 = (sg>>2)&1, b3 = (sg>>3)&1;
    float k8[8];
    #pragma unroll
    for (int m=0;m<8;m++){
      float x = b0 ? v[m] : v[m+8];
      float y = __shfl_xor(x, 1, 64);
      k8[m] = (b0 ? v[m+8] : v[m]) + y;
    }
    float k4[4];
    #pragma unroll
    for (int m=0;m<4;m++){
      float x = b1 ? k8[m] : k8[m+4];
      float y = __shfl_xor(x, 2, 64);
      k4[m] = (b1 ? k8[m+4] : k8[m]) + y;
    }
    float k2[2];
    #pragma unroll
    for (int m=0;m<2;m++){
      float x = b2 ? k4[m] : k4[m+2];
      float y = __shfl_xor(x, 4, 64);
      k2[m] = (b2 ? k4[m+2] : k4[m]) + y;
    }
    float k1;
    {
      float x = b3 ? k2[0] : k2[1];
      float y = __shfl_xor(x, 8, 64);
      k1 = (b3 ? k2[1] : k2[0]) + y;
    }
    k1 += __shfl_xor(k1, 16, 64);
    k1 += __shfl_xor(k1, 32, 64);
    if (sg < 16){
      const int j = b0*8 + b1*4 + b2*2 + b3;   // value index this lane holds
      if (j < 8) pre[rg*8 + j]        = k1;    // L1 row rg*8+j
      else       pre[64 + rg*8 + j-8] = k1;    // L2 row rg*8+(j-8)
    }
  };

  // ---- tail (wave 0): gather gates, apply, publish 32 pairs for g+1 ----
  auto tail = [&](unsigned g, bool d1, bool d2, float xv){
    if (rg == 0){
      const float rsumA = pre[t];        // L1 row t (t = q*16+u)
      const float rsumB = pre[64 + t];   // L2 row t
      const int u = t & 15;
      float pi, pf, pg, po;
      {
        float a0 = __shfl(rsumA, u,      64), e0 = __shfl(rsumB, u,      64);
        float a1 = __shfl(rsumA, u + 16, 64), e1 = __shfl(rsumB, u + 16, 64);
        float a2 = __shfl(rsumA, u + 32, 64), e2 = __shfl(rsumB, u + 32, 64);
        float a3 = __shfl(rsumA, u + 48, 64), e3 = __shfl(rsumB, u + 48, 64);
        const bool l1 = (t < 16);
        pi = l1 ? a0 : e0;
        pf = l1 ? a1 : e1;
        pg = l1 ? a2 : e2;
        po = l1 ? a3 : e3;
      }
      const bool act = (t < 16) ? d1 : ((t < 32) ? d2 : false);
      if (act){
        if (t < 16){
          pi += xv*wx[0] + bias[0];
          pf += xv*wx[1] + bias[1];
          pg += xv*wx[2] + bias[2];
          po += xv*wx[3] + bias[3];
        } else {
          pi += bias[0]; pf += bias[1]; pg += bias[2]; po += bias[3];
        }
        cst  = sigf(pf)*cst + sigf(pi)*tanhf_fast(pg);
        hcur = sigf(po)*tanhf_fast(cst);
      }
      if (t < 32){
        u64 pr = ((u64)(g + 1u) << 32) | (u64)__builtin_bit_cast(unsigned, hcur);
        u64* nb = commu + ((g+1u) & 1u)*SLOTU + wg*LINEU + t;
        __hip_atomic_store(nb, pr, __ATOMIC_RELAXED, AS);
      }
    }
  };

  // o = Wlin . h2 + blin from hvec chunks 2/3; result in ALL wave-0 lanes
  auto computeO = [&](int oi, float& xv){
    if (rg == 0){
      float s = dot4(wl0, ((const float4*)(hvec + 2*STR))[t])
              + dot4(wl1, ((const float4*)(hvec + 3*STR))[t]);
      #pragma unroll
      for (int m=1;m<64;m<<=1) s += __shfl_xor(s, m, 64);
      xv = s + blin0;
      if (wg == 0 && t == 0) out[oi] = xv;
    }
  };

  __syncthreads();   // xrow staged

  unsigned g = 0;

  // ---- teacher: tick g computes L1 step g || L2 step g-1 ----
  for (int tk=0; tk<TT; ++tk, ++g){
    poll_stage(g);                       // hvec = [h1_{g-1} | h2_{g-2}]
    dots_reduce();
    __syncthreads();
    tail(g, true, tk >= 1, xrow[tk]);    // publish [h1_g | h2_{g-1}] pairs
  }

  // ---- drain: L2 step 1023 ----
  poll_stage(g);                         // [h1_1023 | h2_1022]
  dots_reduce();
  __syncthreads();
  tail(g, false, true, 0.f);             // publish [h1_1023 | h2_1023]
  ++g;

  // ---- AR: steps s = 1024..1086, 2 ticks each ----
  for (int s=TT; s<TT+PRED-1; ++s){
    poll_stage(g);                       // [h1_{s-1} | h2_{s-1}]
    float xv = 0.f;
    computeO(s - TT, xv);                // emit out[s-TT] (o_{s-1})
    dots_reduce();
    __syncthreads();
    tail(g, true, false, xv);            // publish [h1_s | h2_{s-1}]
    ++g;

    poll_stage(g);                       // [h1_s | h2_{s-1}]
    dots_reduce();
    __syncthreads();
    tail(g, false, true, 0.f);           // publish [h1_s | h2_s]
    ++g;
  }

  // ---- final output o_1086 ----
  poll_stage(g);                         // [h1_1086 | h2_1086]
  float xv;
  computeO(PRED - 1, xv);
}

extern "C" void kernel_launch(void* const* d_in, const int* in_sizes, int n_in,
                              void* d_out, int out_size, void* d_ws, size_t ws_size,
                              hipStream_t stream) {
  const float* input = (const float*)d_in[0];
  // d_in[1] = pred_len (fixed 64, baked in)
  const float* Wih1 = (const float*)d_in[2];
  const float* Whh1 = (const float*)d_in[3];
  const float* bih1 = (const float*)d_in[4];
  const float* bhh1 = (const float*)d_in[5];
  const float* Wih2 = (const float*)d_in[6];
  const float* Whh2 = (const float*)d_in[7];
  const float* bih2 = (const float*)d_in[8];
  const float* bhh2 = (const float*)d_in[9];
  const float* Wlin = (const float*)d_in[10];
  const float* blin = (const float*)d_in[11];

  // zero comm: u64 zero pairs == (tag 0, h=0.0f) -> valid initial state
  // 2 slots x 32 lines x 256 B = 16 KiB
  hipMemsetAsync(d_ws, 0, (size_t)2 * SLOTU * sizeof(u64), stream);

  lstm2_kernel<<<dim3(G), dim3(NT), 0, stream>>>(
      input, Wih1, Whh1, bih1, bhh1, Wih2, Whh2, bih2, bhh2, Wlin, blin,
      (float*)d_out, (float*)d_ws);
}